// Round 5
// baseline (15051.572 us; speedup 1.0000x reference)
//
#include <hip/hip_runtime.h>

#define LAYERS 6
#define BB 10
#define TT 2048
#define II 128
#define HH 256
#define GPL 32          // blocks per layer
#define DEPTH 8         // h ring-buffer depth (power of 2)
#define NTH 256
#define NCOL 8          // h-columns per block
#define NROW 32         // gate rows per block (4 gates x 8 cols)
#define HCSTR 520       // padded LDS stride for h_cat rows
#define RSTR 328        // red row stride: 328*4 B, 16B-aligned, bank offset 8 -> clean
#define FLPAD 16        // ints per flag slot (64 B padding)

struct Smem {
    union {
        float hc[BB][HCSTR];     // staged [x_t | h_below , h_own] per batch
        float red[4][RSTR];      // 4 K-partials x 320 gate outputs (aliased, phase-disjoint)
    } u;
    float cst[NCOL][BB];
    float bias_s[NROW];
};

__device__ __forceinline__ float fsig(float x) { return 1.0f / (1.0f + __expf(-x)); }
__device__ __forceinline__ float ftanh(float x) {
    x = fminf(fmaxf(x, -15.0f), 15.0f);
    float e = __expf(2.0f * x);
    return (e - 1.0f) / (e + 1.0f);
}
__device__ __forceinline__ float ld_agent(const float* p) {
    // coherent LLC read (sc1) — same path the flag polling uses; no fence needed
    return __hip_atomic_load(p, __ATOMIC_RELAXED, __HIP_MEMORY_SCOPE_AGENT);
}
// VALU cross-lane add: v += lane-permuted(v). CTRL: 0xB1=xor1, 0x4E=xor2, 0x128=row_ror:8 (=xor8)
template <int CTRL>
__device__ __forceinline__ float dpp_xadd(float v) {
    int t = __builtin_amdgcn_mov_dpp(__float_as_int(v), CTRL, 0xf, 0xf, true);
    return v + __int_as_float(t);
}

// CH4 = float4-chunks per (thread, batch): 4 -> K=512 (layers 1..5), 3 -> K=384 (layer 0)
template <int CH4>
__device__ void run_layer(Smem& sm, int l, int s,
                          const float* __restrict__ x,
                          const float* __restrict__ h0,
                          const float* __restrict__ c0,
                          const float* __restrict__ Wih0,
                          const float* __restrict__ Wih,
                          const float* __restrict__ Whh,
                          const float* __restrict__ bih,
                          const float* __restrict__ bhh,
                          float* __restrict__ out,
                          int* flags, float* hring)
{
    constexpr int K = CH4 * 128;   // 512 or 384
    constexpr int F = K - HH;      // 256 or 128 (input-feature width)
    constexpr int XC = CH4 - 2;    // x-part chunks; h-part is chunks XC..CH4-1
    const int tid = threadIdx.x;
    const int kc  = tid & 31;      // K-split lane (32 chunks)
    const int rg  = tid >> 5;      // row group 0..7
    const int lane = tid & 63;

    const float* WihL = (F == II) ? Wih0 : (Wih + (size_t)(l - 1) * 4 * HH * HH);
    const float* WhhL = Whh + (size_t)l * 4 * HH * HH;

    // ---- persistent weight registers: 4 rows x CH4 float4 ----
    float4 wreg[4][CH4];
    #pragma unroll
    for (int ri = 0; ri < 4; ++ri) {
        const int rloc = rg * 4 + ri;                            // 0..31
        const int gr = (rloc >> 3) * HH + s * NCOL + (rloc & 7); // global gate row
        #pragma unroll
        for (int i4 = 0; i4 < CH4; ++i4) {
            const int k0 = (i4 * 32 + kc) * 4;
            float tmp[4];
            #pragma unroll
            for (int c = 0; c < 4; ++c) {
                const int kk = k0 + c;
                tmp[c] = (kk < F) ? WihL[(size_t)gr * F + kk]
                                  : WhhL[(size_t)gr * HH + (kk - F)];
            }
            wreg[ri][i4] = make_float4(tmp[0], tmp[1], tmp[2], tmp[3]);
        }
    }
    if (tid < NROW) {
        const int gr = (tid >> 3) * HH + s * NCOL + (tid & 7);
        sm.bias_s[tid] = bih[l * 4 * HH + gr] + bhh[l * 4 * HH + gr];
    }
    if (tid < NCOL * BB) {
        const int j = tid & 7, b = tid >> 3;
        sm.cst[j][b] = c0[((size_t)l * BB + b) * HH + s * NCOL + j];
    }
    __syncthreads();

    float* const myring = hring + (size_t)l * DEPTH * BB * HH;

    for (int t = 0; t < TT; ++t) {
        // ---- P0: below-ready + back-pressure polls (every wave; usually instant) ----
        {
            bool act; const int* p; int tgt;
            if (lane < 32) {
                act = (l > 0);
                p = flags + ((l - 1) * GPL + lane) * FLPAD; tgt = t + 1;
            } else {
                act = (l < LAYERS - 1) && (t >= DEPTH);
                p = flags + ((l + 1) * GPL + (lane - 32)) * FLPAD; tgt = t - DEPTH + 1;
            }
            if (__ballot(act)) {
                for (;;) {
                    int v = act ? __hip_atomic_load(p, __ATOMIC_RELAXED, __HIP_MEMORY_SCOPE_AGENT)
                                : 0x7fffffff;
                    if (__ballot(act && v < tgt) == 0) break;
                    __builtin_amdgcn_s_sleep(2);
                }
            }
        }

        // ---- P1a: issue below/x gather into registers (latency overlapped with P3 poll) ----
        float tb[10];
        float4 xq[2];
        if (F == II) {
            #pragma unroll
            for (int j = 0; j < 2; ++j) {
                const int q = tid + j * NTH;
                if (q < BB * (II / 4)) {
                    const int b = q >> 5, qq = q & 31;
                    xq[j] = *(const float4*)&x[((size_t)b * TT + t) * II + qq * 4];
                }
            }
        } else {
            const float* below = hring + ((size_t)(l - 1) * DEPTH + (t & (DEPTH - 1))) * BB * HH;
            #pragma unroll
            for (int i = 0; i < 10; ++i)
                tb[i] = ld_agent(&below[tid + i * NTH]);
        }

        // ---- P3: own-layer handshake (critical; below-gather in flight) ----
        if (t > 0) {
            const int* p = flags + (l * GPL + (lane & 31)) * FLPAD;
            for (;;) {
                int v = __hip_atomic_load(p, __ATOMIC_RELAXED, __HIP_MEMORY_SCOPE_AGENT);
                if (__ballot(v < t) == 0) break;
                __builtin_amdgcn_s_sleep(1);
            }
        }

        // ---- P4a: issue own-h gather (latency overlapped with P2 x-GEMM) ----
        float to_[10];
        {
            const float* own = (t == 0) ? (h0 + (size_t)l * BB * HH)
                                        : (myring + (size_t)((t - 1) & (DEPTH - 1)) * BB * HH);
            #pragma unroll
            for (int i = 0; i < 10; ++i)
                to_[i] = ld_agent(&own[tid + i * NTH]);
        }

        // ---- P1b: below/x regs -> LDS lower region ----
        if (F == II) {
            #pragma unroll
            for (int j = 0; j < 2; ++j) {
                const int q = tid + j * NTH;
                if (q < BB * (II / 4))
                    *(float4*)&sm.u.hc[q >> 5][(q & 31) * 4] = xq[j];
            }
        } else {
            #pragma unroll
            for (int i = 0; i < 10; ++i) {
                const int q = tid + i * NTH;
                sm.u.hc[q >> 8][q & 255] = tb[i];
            }
        }
        __syncthreads();   // B1: lower region staged

        // ---- P2: x-part GEMM (own-h loads still in flight) ----
        float acc[4][BB];
        #pragma unroll
        for (int ri = 0; ri < 4; ++ri)
            #pragma unroll
            for (int b = 0; b < BB; ++b) acc[ri][b] = 0.0f;

        #pragma unroll
        for (int i4 = 0; i4 < XC; ++i4) {
            const int col = (i4 * 32 + kc) * 4;
            #pragma unroll
            for (int b = 0; b < BB; ++b) {
                const float4 h4 = *(const float4*)&sm.u.hc[b][col];
                #pragma unroll
                for (int ri = 0; ri < 4; ++ri) {
                    acc[ri][b] = fmaf(wreg[ri][i4].x, h4.x, acc[ri][b]);
                    acc[ri][b] = fmaf(wreg[ri][i4].y, h4.y, acc[ri][b]);
                    acc[ri][b] = fmaf(wreg[ri][i4].z, h4.z, acc[ri][b]);
                    acc[ri][b] = fmaf(wreg[ri][i4].w, h4.w, acc[ri][b]);
                }
            }
        }

        // ---- P4b: own-h regs -> LDS upper region ----
        #pragma unroll
        for (int i = 0; i < 10; ++i) {
            const int q = tid + i * NTH;
            sm.u.hc[q >> 8][F + (q & 255)] = to_[i];
        }
        __syncthreads();   // B2: upper region staged

        // ---- P5: h-part GEMM (the critical-path compute) ----
        #pragma unroll
        for (int i4 = XC; i4 < CH4; ++i4) {
            const int col = (i4 * 32 + kc) * 4;
            #pragma unroll
            for (int b = 0; b < BB; ++b) {
                const float4 h4 = *(const float4*)&sm.u.hc[b][col];
                #pragma unroll
                for (int ri = 0; ri < 4; ++ri) {
                    acc[ri][b] = fmaf(wreg[ri][i4].x, h4.x, acc[ri][b]);
                    acc[ri][b] = fmaf(wreg[ri][i4].y, h4.y, acc[ri][b]);
                    acc[ri][b] = fmaf(wreg[ri][i4].z, h4.z, acc[ri][b]);
                    acc[ri][b] = fmaf(wreg[ri][i4].w, h4.w, acc[ri][b]);
                }
            }
        }

        // ---- P5b: DPP tree-reduce over kc bits {0,1,3}: 32 -> 4 partials (pure VALU) ----
        #pragma unroll
        for (int ri = 0; ri < 4; ++ri)
            #pragma unroll
            for (int b = 0; b < BB; ++b) {
                float v = acc[ri][b];
                v = dpp_xadd<0xB1>(v);    // quad_perm [1,0,3,2]  : + lane^1
                v = dpp_xadd<0x4E>(v);    // quad_perm [2,3,0,1]  : + lane^2
                v = dpp_xadd<0x128>(v);   // row_ror:8            : + lane^8
                acc[ri][b] = v;
            }
        __syncthreads();   // B3: all hc reads done; red aliases hc

        // ---- P6: dump the 4 surviving partials (kc in {0,4,16,20}), 10 x b128 each ----
        if ((kc & 0x0B) == 0) {
            const int p = ((kc >> 2) & 1) | ((kc >> 3) & 2);   // {0,4,16,20} -> {0,1,2,3}
            const float* a = &acc[0][0];
            float* dst = &sm.u.red[p][rg * 40];
            #pragma unroll
            for (int n = 0; n < 10; ++n)
                *(float4*)&dst[n * 4] = make_float4(a[n*4], a[n*4+1], a[n*4+2], a[n*4+3]);
        }
        __syncthreads();   // B4: partials visible

        // ---- P8: nonlinearities + state update (80 threads, reads partials directly) ----
        if (tid < NCOL * BB) {
            const int j = tid & 7, b = tid >> 3;
            float g4[4];
            #pragma unroll
            for (int g = 0; g < 4; ++g) {
                const int col = (g * 8 + j) * 10 + b;
                g4[g] = ((sm.u.red[0][col] + sm.u.red[1][col])
                       + (sm.u.red[2][col] + sm.u.red[3][col])) + sm.bias_s[g * 8 + j];
            }
            float c = sm.cst[j][b];
            c = fsig(g4[1]) * c + fsig(g4[0]) * ftanh(g4[2]);
            const float h = fsig(g4[3]) * ftanh(c);
            sm.cst[j][b] = c;
            // sc1 write-through store: lands at the coherence point (LLC)
            __hip_atomic_store(&myring[(size_t)(t & (DEPTH - 1)) * BB * HH + b * HH + s * NCOL + j],
                               h, __ATOMIC_RELAXED, __HIP_MEMORY_SCOPE_AGENT);
            if (t == TT - 1)
                out[((size_t)l * BB + b) * HH + s * NCOL + j] = c;
        }
        __syncthreads();   // B5: per-wave vmcnt(0) before s_barrier drains the h stores
        if (tid == 0)
            __hip_atomic_store(flags + (l * GPL + s) * FLPAD, t + 1,
                               __ATOMIC_RELEASE, __HIP_MEMORY_SCOPE_AGENT);
    }
}

__global__ __launch_bounds__(NTH, 1)
void lstm_persistent(const float* __restrict__ x, const float* __restrict__ h0,
                     const float* __restrict__ c0, const float* __restrict__ Wih0,
                     const float* __restrict__ Wih, const float* __restrict__ Whh,
                     const float* __restrict__ bih, const float* __restrict__ bhh,
                     float* __restrict__ out, int* flags, float* hring)
{
    __shared__ Smem sm;
    const int l = blockIdx.x / GPL;
    const int s = blockIdx.x % GPL;
    if (l == 0)
        run_layer<3>(sm, l, s, x, h0, c0, Wih0, Wih, Whh, bih, bhh, out, flags, hring);
    else
        run_layer<4>(sm, l, s, x, h0, c0, Wih0, Wih, Whh, bih, bhh, out, flags, hring);
}

extern "C" void kernel_launch(void* const* d_in, const int* in_sizes, int n_in,
                              void* d_out, int out_size, void* d_ws, size_t ws_size,
                              hipStream_t stream) {
    const float* x    = (const float*)d_in[0];
    const float* h0   = (const float*)d_in[1];
    const float* c0   = (const float*)d_in[2];
    const float* Wih0 = (const float*)d_in[3];
    const float* Wih  = (const float*)d_in[4];
    const float* Whh  = (const float*)d_in[5];
    const float* bih  = (const float*)d_in[6];
    const float* bhh  = (const float*)d_in[7];
    float* out  = (float*)d_out;

    int*   flags = (int*)d_ws;                        // [L][GPL] padded to 64B each
    float* hring = (float*)((char*)d_ws + 16384);     // [L][DEPTH][B][H] ring

    (void)hipMemsetAsync(d_ws, 0, 16384, stream);     // ws is poisoned 0xAA each launch
    hipLaunchKernelGGL(lstm_persistent, dim3(LAYERS * GPL), dim3(NTH), 0, stream,
                       x, h0, c0, Wih0, Wih, Whh, bih, bhh, out, flags, hring);
}

// Round 6
// 12755.157 us; speedup vs baseline: 1.1800x; 1.1800x over previous
//
#include <hip/hip_runtime.h>

#define LAYERS 6
#define BB 10
#define TT 2048
#define II 128
#define HH 256
#define GPL 32          // blocks per layer
#define DEPTH 8         // h ring-buffer depth (power of 2)
#define NTH 256
#define NCOL 8          // h-columns per block
#define NROW 32         // gate rows per block (4 gates x 8 cols)
#define HCSTR 520       // padded LDS stride for h_cat rows
#define PSTR 392        // red p-plane stride: 392 mod 32 = 8 -> planes hit different banks
#define FLPAD 16        // ints per flag slot (64 B padding)

struct __align__(16) Smem {
    union {
        float hc[BB][HCSTR];     // staged [x_t | h_below , h_own] per batch
        float red[4][PSTR];      // 4 K-partials x 32 rows x 12-stride (aliased, phase-disjoint)
    } u;
    float cst[NCOL][BB];
    float bias_s[NROW];
};

__device__ __forceinline__ float fsig(float x) { return 1.0f / (1.0f + __expf(-x)); }
__device__ __forceinline__ float ftanh(float x) {
    x = fminf(fmaxf(x, -15.0f), 15.0f);
    float e = __expf(2.0f * x);
    return (e - 1.0f) / (e + 1.0f);
}
__device__ __forceinline__ float ld_agent(const float* p) {
    // coherent LLC read (sc1) — same path the flag polling uses; no fence needed
    return __hip_atomic_load(p, __ATOMIC_RELAXED, __HIP_MEMORY_SCOPE_AGENT);
}
// VALU cross-lane add: v += lane-permuted(v). CTRL: 0xB1=xor1, 0x4E=xor2, 0x128=row_ror:8 (=xor8)
template <int CTRL>
__device__ __forceinline__ float dpp_xadd(float v) {
    int t = __builtin_amdgcn_mov_dpp(__float_as_int(v), CTRL, 0xf, 0xf, true);
    return v + __int_as_float(t);
}

// CH4 = float4-chunks per (thread, batch): 4 -> K=512 (layers 1..5), 3 -> K=384 (layer 0)
template <int CH4>
__device__ void run_layer(Smem& sm, int l, int s,
                          const float* __restrict__ x,
                          const float* __restrict__ h0,
                          const float* __restrict__ c0,
                          const float* __restrict__ Wih0,
                          const float* __restrict__ Wih,
                          const float* __restrict__ Whh,
                          const float* __restrict__ bih,
                          const float* __restrict__ bhh,
                          float* __restrict__ out,
                          int* flags, float* hring)
{
    constexpr int K = CH4 * 128;   // 512 or 384
    constexpr int F = K - HH;      // 256 or 128 (input-feature width)
    constexpr int XC = CH4 - 2;    // x-part chunks; h-part is chunks XC..CH4-1
    const int tid = threadIdx.x;
    const int kc  = tid & 31;      // K-split lane (32 chunks)
    const int rg  = tid >> 5;      // row group 0..7
    const int lane = tid & 63;

    const float* WihL = (F == II) ? Wih0 : (Wih + (size_t)(l - 1) * 4 * HH * HH);
    const float* WhhL = Whh + (size_t)l * 4 * HH * HH;

    // ---- persistent weight registers: 4 rows x CH4 float4 ----
    float4 wreg[4][CH4];
    #pragma unroll
    for (int ri = 0; ri < 4; ++ri) {
        const int rloc = rg * 4 + ri;                            // 0..31
        const int gr = (rloc >> 3) * HH + s * NCOL + (rloc & 7); // global gate row
        #pragma unroll
        for (int i4 = 0; i4 < CH4; ++i4) {
            const int k0 = (i4 * 32 + kc) * 4;
            float tmp[4];
            #pragma unroll
            for (int c = 0; c < 4; ++c) {
                const int kk = k0 + c;
                tmp[c] = (kk < F) ? WihL[(size_t)gr * F + kk]
                                  : WhhL[(size_t)gr * HH + (kk - F)];
            }
            wreg[ri][i4] = make_float4(tmp[0], tmp[1], tmp[2], tmp[3]);
        }
    }
    if (tid < NROW) {
        const int gr = (tid >> 3) * HH + s * NCOL + (tid & 7);
        sm.bias_s[tid] = bih[l * 4 * HH + gr] + bhh[l * 4 * HH + gr];
    }
    if (tid < NCOL * BB) {
        const int j = tid & 7, b = tid >> 3;
        sm.cst[j][b] = c0[((size_t)l * BB + b) * HH + s * NCOL + j];
    }
    __syncthreads();

    float* const myring = hring + (size_t)l * DEPTH * BB * HH;

    for (int t = 0; t < TT; ++t) {
        // ---- P0: below-ready + back-pressure polls (every wave; usually instant) ----
        {
            bool act; const int* p; int tgt;
            if (lane < 32) {
                act = (l > 0);
                p = flags + ((l - 1) * GPL + lane) * FLPAD; tgt = t + 1;
            } else {
                act = (l < LAYERS - 1) && (t >= DEPTH);
                p = flags + ((l + 1) * GPL + (lane - 32)) * FLPAD; tgt = t - DEPTH + 1;
            }
            if (__ballot(act)) {
                for (;;) {
                    int v = act ? __hip_atomic_load(p, __ATOMIC_RELAXED, __HIP_MEMORY_SCOPE_AGENT)
                                : 0x7fffffff;
                    if (__ballot(act && v < tgt) == 0) break;
                    __builtin_amdgcn_s_sleep(2);
                }
            }
        }

        // ---- P1a: issue below/x gather into registers (latency overlapped with P3 poll) ----
        float tb[10];
        float4 xq[2];
        if (F == II) {
            #pragma unroll
            for (int j = 0; j < 2; ++j) {
                const int q = tid + j * NTH;
                if (q < BB * (II / 4)) {
                    const int b = q >> 5, qq = q & 31;
                    xq[j] = *(const float4*)&x[((size_t)b * TT + t) * II + qq * 4];
                }
            }
        } else {
            const float* below = hring + ((size_t)(l - 1) * DEPTH + (t & (DEPTH - 1))) * BB * HH;
            #pragma unroll
            for (int i = 0; i < 10; ++i)
                tb[i] = ld_agent(&below[tid + i * NTH]);
        }

        // ---- P3: own-layer handshake (critical; below-gather in flight) ----
        if (t > 0) {
            const int* p = flags + (l * GPL + (lane & 31)) * FLPAD;
            for (;;) {
                int v = __hip_atomic_load(p, __ATOMIC_RELAXED, __HIP_MEMORY_SCOPE_AGENT);
                if (__ballot(v < t) == 0) break;
                __builtin_amdgcn_s_sleep(1);
            }
        }

        // ---- P4a: issue own-h gather (latency overlapped with P2 x-GEMM) ----
        float to_[10];
        {
            const float* own = (t == 0) ? (h0 + (size_t)l * BB * HH)
                                        : (myring + (size_t)((t - 1) & (DEPTH - 1)) * BB * HH);
            #pragma unroll
            for (int i = 0; i < 10; ++i)
                to_[i] = ld_agent(&own[tid + i * NTH]);
        }

        // ---- P1b: below/x regs -> LDS lower region ----
        if (F == II) {
            #pragma unroll
            for (int j = 0; j < 2; ++j) {
                const int q = tid + j * NTH;
                if (q < BB * (II / 4))
                    *(float4*)&sm.u.hc[q >> 5][(q & 31) * 4] = xq[j];
            }
        } else {
            #pragma unroll
            for (int i = 0; i < 10; ++i) {
                const int q = tid + i * NTH;
                sm.u.hc[q >> 8][q & 255] = tb[i];
            }
        }
        __syncthreads();   // B1: lower region staged

        // ---- P2: x-part GEMM (own-h loads still in flight) ----
        float acc[4][BB];
        #pragma unroll
        for (int ri = 0; ri < 4; ++ri)
            #pragma unroll
            for (int b = 0; b < BB; ++b) acc[ri][b] = 0.0f;

        #pragma unroll
        for (int i4 = 0; i4 < XC; ++i4) {
            const int col = (i4 * 32 + kc) * 4;
            #pragma unroll
            for (int b = 0; b < BB; ++b) {
                const float4 h4 = *(const float4*)&sm.u.hc[b][col];
                #pragma unroll
                for (int ri = 0; ri < 4; ++ri) {
                    acc[ri][b] = fmaf(wreg[ri][i4].x, h4.x, acc[ri][b]);
                    acc[ri][b] = fmaf(wreg[ri][i4].y, h4.y, acc[ri][b]);
                    acc[ri][b] = fmaf(wreg[ri][i4].z, h4.z, acc[ri][b]);
                    acc[ri][b] = fmaf(wreg[ri][i4].w, h4.w, acc[ri][b]);
                }
            }
        }

        // ---- P4b: own-h regs -> LDS upper region ----
        #pragma unroll
        for (int i = 0; i < 10; ++i) {
            const int q = tid + i * NTH;
            sm.u.hc[q >> 8][F + (q & 255)] = to_[i];
        }
        __syncthreads();   // B2: upper region staged

        // ---- P5: h-part GEMM (the critical-path compute) ----
        #pragma unroll
        for (int i4 = XC; i4 < CH4; ++i4) {
            const int col = (i4 * 32 + kc) * 4;
            #pragma unroll
            for (int b = 0; b < BB; ++b) {
                const float4 h4 = *(const float4*)&sm.u.hc[b][col];
                #pragma unroll
                for (int ri = 0; ri < 4; ++ri) {
                    acc[ri][b] = fmaf(wreg[ri][i4].x, h4.x, acc[ri][b]);
                    acc[ri][b] = fmaf(wreg[ri][i4].y, h4.y, acc[ri][b]);
                    acc[ri][b] = fmaf(wreg[ri][i4].z, h4.z, acc[ri][b]);
                    acc[ri][b] = fmaf(wreg[ri][i4].w, h4.w, acc[ri][b]);
                }
            }
        }

        // ---- P5b: DPP tree-reduce over kc bits {0,1,3}: 32 -> 4 partials (pure VALU) ----
        #pragma unroll
        for (int ri = 0; ri < 4; ++ri)
            #pragma unroll
            for (int b = 0; b < BB; ++b) {
                float v = acc[ri][b];
                v = dpp_xadd<0xB1>(v);    // quad_perm [1,0,3,2]  : + lane^1
                v = dpp_xadd<0x4E>(v);    // quad_perm [2,3,0,1]  : + lane^2
                v = dpp_xadd<0x128>(v);   // row_ror:8            : + lane^8
                acc[ri][b] = v;
            }
        __syncthreads();   // B3: all hc reads done; red aliases hc

        // ---- P6: dump the 4 surviving partials (kc in {0,4,16,20}) ----
        // CONSTANT indices into acc only (SROA-safe: no flattened pointer, no cross-subarray GEP)
        if ((kc & 0x0B) == 0) {
            const int p = ((kc >> 2) & 1) | ((kc >> 3) & 2);   // {0,4,16,20} -> {0,1,2,3}
            float* dst = &sm.u.red[p][(rg * 4) * 12];
            #pragma unroll
            for (int ri = 0; ri < 4; ++ri) {
                *(float4*)&dst[ri * 12 + 0] =
                    make_float4(acc[ri][0], acc[ri][1], acc[ri][2], acc[ri][3]);
                *(float4*)&dst[ri * 12 + 4] =
                    make_float4(acc[ri][4], acc[ri][5], acc[ri][6], acc[ri][7]);
                *(float2*)&dst[ri * 12 + 8] = make_float2(acc[ri][8], acc[ri][9]);
            }
        }
        __syncthreads();   // B4: partials visible

        // ---- P8: nonlinearities + state update (80 threads, reads partials directly) ----
        if (tid < NCOL * BB) {
            const int j = tid & 7, b = tid >> 3;
            float g4[4];
            #pragma unroll
            for (int g = 0; g < 4; ++g) {
                const int col = (g * 8 + j) * 12 + b;
                g4[g] = ((sm.u.red[0][col] + sm.u.red[1][col])
                       + (sm.u.red[2][col] + sm.u.red[3][col])) + sm.bias_s[g * 8 + j];
            }
            float c = sm.cst[j][b];
            c = fsig(g4[1]) * c + fsig(g4[0]) * ftanh(g4[2]);
            const float h = fsig(g4[3]) * ftanh(c);
            sm.cst[j][b] = c;
            // sc1 write-through store: lands at the coherence point (LLC)
            __hip_atomic_store(&myring[(size_t)(t & (DEPTH - 1)) * BB * HH + b * HH + s * NCOL + j],
                               h, __ATOMIC_RELAXED, __HIP_MEMORY_SCOPE_AGENT);
            if (t == TT - 1)
                out[((size_t)l * BB + b) * HH + s * NCOL + j] = c;
        }
        __syncthreads();   // B5: per-wave vmcnt(0) before s_barrier drains the h stores
        if (tid == 0)
            __hip_atomic_store(flags + (l * GPL + s) * FLPAD, t + 1,
                               __ATOMIC_RELEASE, __HIP_MEMORY_SCOPE_AGENT);
    }
}

__global__ __launch_bounds__(NTH, 1)
void lstm_persistent(const float* __restrict__ x, const float* __restrict__ h0,
                     const float* __restrict__ c0, const float* __restrict__ Wih0,
                     const float* __restrict__ Wih, const float* __restrict__ Whh,
                     const float* __restrict__ bih, const float* __restrict__ bhh,
                     float* __restrict__ out, int* flags, float* hring)
{
    __shared__ Smem sm;
    const int l = blockIdx.x / GPL;
    const int s = blockIdx.x % GPL;
    if (l == 0)
        run_layer<3>(sm, l, s, x, h0, c0, Wih0, Wih, Whh, bih, bhh, out, flags, hring);
    else
        run_layer<4>(sm, l, s, x, h0, c0, Wih0, Wih, Whh, bih, bhh, out, flags, hring);
}

extern "C" void kernel_launch(void* const* d_in, const int* in_sizes, int n_in,
                              void* d_out, int out_size, void* d_ws, size_t ws_size,
                              hipStream_t stream) {
    const float* x    = (const float*)d_in[0];
    const float* h0   = (const float*)d_in[1];
    const float* c0   = (const float*)d_in[2];
    const float* Wih0 = (const float*)d_in[3];
    const float* Wih  = (const float*)d_in[4];
    const float* Whh  = (const float*)d_in[5];
    const float* bih  = (const float*)d_in[6];
    const float* bhh  = (const float*)d_in[7];
    float* out  = (float*)d_out;

    int*   flags = (int*)d_ws;                        // [L][GPL] padded to 64B each
    float* hring = (float*)((char*)d_ws + 16384);     // [L][DEPTH][B][H] ring

    (void)hipMemsetAsync(d_ws, 0, 16384, stream);     // ws is poisoned 0xAA each launch
    hipLaunchKernelGGL(lstm_persistent, dim3(LAYERS * GPL), dim3(NTH), 0, stream,
                       x, h0, c0, Wih0, Wih, Whh, bih, bhh, out, flags, hring);
}